// Round 1
// baseline (185.764 us; speedup 1.0000x reference)
//
#include <hip/hip_runtime.h>
#include <stdint.h>

// Problem constants
#define Bb 4
#define Nn 2048
#define Dd 512
#define Hh 8
#define BN 8192   // Bb*Nn

typedef __attribute__((ext_vector_type(4))) float f32x4;
typedef __attribute__((ext_vector_type(8))) short s16x8;

// ---- workspace layout (bytes) ----
static constexpr size_t OFF_FLAG  = 0;
static constexpr size_t OFF_XB    = 1024;                                   // 8192x512 bf16
static constexpr size_t OFF_WQKVT = OFF_XB    + (size_t)2 * BN * Dd;        // 1536x512 bf16
static constexpr size_t OFF_WOUTT = OFF_WQKVT + (size_t)2 * 3 * Dd * Dd;    // 512x512 bf16
static constexpr size_t OFF_MASKP = OFF_WOUTT + (size_t)2 * Dd * Dd;        // B*N*32 u64
static constexpr size_t OFF_Q     = OFF_MASKP + (size_t)8 * Bb * Nn * (Nn / 64); // (B,H,N,64) bf16
static constexpr size_t OFF_K     = OFF_Q     + (size_t)2 * BN * Dd;
static constexpr size_t OFF_VT    = OFF_K     + (size_t)2 * BN * Dd;        // (B,H,64,N) bf16
static constexpr size_t OFF_AO    = OFF_VT    + (size_t)2 * BN * Dd;        // (B,N,512) bf16

__device__ inline unsigned short f2bf(float f) {
  union { float f; unsigned int u; } v; v.f = f;
  const unsigned int u = v.u;
  return (unsigned short)((u + 0x7fffu + ((u >> 16) & 1u)) >> 16);  // RNE
}

// ---- mask dtype detection: bool-as-byte vs wider (int32/float32) ----
// Diagonal is guaranteed True. Under byte storage, bytes at i*(N+1) are all
// nonzero. Under 4-byte storage, byte offsets i*2049 with i%4!=0 land on the
// upper bytes of small ints/1.0f floats and read 0.
__global__ void detect_mask_kernel(const unsigned char* __restrict__ mb, int* __restrict__ flag) {
  const int l = threadIdx.x;              // 64 threads
  const int i = l + 1;
  const int ok = mb[(size_t)i * (Nn + 1)] != 0;
  const unsigned long long bal = __ballot(ok);
  if (l == 0) *flag = (bal == 0xFFFFFFFFFFFFFFFFull) ? 1 : 0;
}

__global__ void cvt_x_kernel(const float* __restrict__ x, unsigned short* __restrict__ xb, int n4) {
  int i = blockIdx.x * blockDim.x + threadIdx.x;
  const int stride = gridDim.x * blockDim.x;
  for (; i < n4; i += stride) {
    const float4 v = ((const float4*)x)[i];
    ushort4 o;
    o.x = f2bf(v.x); o.y = f2bf(v.y); o.z = f2bf(v.z); o.w = f2bf(v.w);
    ((ushort4*)xb)[i] = o;
  }
}

// w (R x C) fp32 row-major -> wT (C x R) bf16 row-major
__global__ void cvt_wT_kernel(const float* __restrict__ w, unsigned short* __restrict__ wT, int R, int C) {
  int i = blockIdx.x * blockDim.x + threadIdx.x;
  const int stride = gridDim.x * blockDim.x;
  const int total = R * C;
  for (; i < total; i += stride) {
    const int r = i / C, c = i - r * C;
    wT[(size_t)c * R + r] = f2bf(w[i]);
  }
}

// pack mask into bits: word w holds keys [w*64, w*64+64), bit = lane via ballot
__global__ void pack_mask_kernel(const unsigned char* __restrict__ mb, const int* __restrict__ mi,
                                 const int* __restrict__ flag, unsigned long long* __restrict__ mp,
                                 int nwords) {
  const int lane = threadIdx.x & 63;
  int gw = (blockIdx.x * blockDim.x + threadIdx.x) >> 6;
  const int nw = (gridDim.x * blockDim.x) >> 6;
  const int bytemode = *flag;
  for (; gw < nwords; gw += nw) {
    const size_t idx = (size_t)gw * 64 + lane;
    int v;
    if (bytemode) v = mb[idx]; else v = mi[idx];   // real branch: no OOB speculation
    const unsigned long long bits = __ballot(v != 0);
    if (lane == 0) mp[gw] = bits;
  }
}

// ---- 128x128 bf16 TN GEMM core, K=512, BK=64, double-buffered LDS ----
// MODE 0: epilogue scatters Q,K (B,H,N,64) and V transposed (B,H,64,N)
// MODE 1: epilogue adds bias, LeakyReLU, stores fp32
template <int MODE>
__global__ __launch_bounds__(256, 2) void gemm128(
    const unsigned short* __restrict__ A,   // M x 512 bf16, k-contig
    const unsigned short* __restrict__ BT,  // Ncols x 512 bf16, k-contig
    unsigned short* __restrict__ qb, unsigned short* __restrict__ kb,
    unsigned short* __restrict__ vt, const float* __restrict__ bias,
    float* __restrict__ outp) {
  __shared__ unsigned short Al[2][8192];  // 128 rows x 64 k (128B rows, 8 slots of 16B)
  __shared__ unsigned short Bl[2][8192];
  const int tid = threadIdx.x;
  const int lane = tid & 63, wv = tid >> 6;
  const int g = lane >> 4, n16 = lane & 15;
  const int m0 = blockIdx.x * 128;
  const int c0 = blockIdx.y * 128;
  const int wm = wv >> 1, wn = wv & 1;   // 2x2 waves, 64x64 each

  f32x4 acc[4][4] = {};

  auto stage = [&](int buf, int t) {
#pragma unroll
    for (int j = 0; j < 4; ++j) {
      const int base = (wv * 4 + j) * 1024;       // wave-uniform LDS byte base
      const int o = base + lane * 16;             // this lane's dest (HW adds lane*16)
      const int r = o >> 7;                       // row 0..127
      const int sl = ((o >> 4) & 7) ^ (r & 7);    // pre-swizzled logical slot
      const unsigned short* ga = A + (size_t)(m0 + r) * 512 + t * 64 + sl * 8;
      __builtin_amdgcn_global_load_lds(
          (const __attribute__((address_space(1))) uint32_t*)ga,
          (__attribute__((address_space(3))) uint32_t*)&Al[buf][base / 2], 16, 0, 0);
      const unsigned short* gb = BT + (size_t)(c0 + r) * 512 + t * 64 + sl * 8;
      __builtin_amdgcn_global_load_lds(
          (const __attribute__((address_space(1))) uint32_t*)gb,
          (__attribute__((address_space(3))) uint32_t*)&Bl[buf][base / 2], 16, 0, 0);
    }
  };

  stage(0, 0);
  __syncthreads();
  int cur = 0;
  for (int t = 0; t < 8; ++t) {
    if (t < 7) stage(cur ^ 1, t + 1);
    s16x8 af[4][2], bfr[4][2];
#pragma unroll
    for (int f = 0; f < 4; ++f) {
#pragma unroll
      for (int kc = 0; kc < 2; ++kc) {
        const int rr = wm * 64 + f * 16 + n16;
        const int cc = wn * 64 + f * 16 + n16;
        const int sl = kc * 4 + g;
        af[f][kc]  = *(const s16x8*)&Al[cur][(rr * 128 + ((sl ^ (rr & 7)) * 16)) / 2];
        bfr[f][kc] = *(const s16x8*)&Bl[cur][(cc * 128 + ((sl ^ (cc & 7)) * 16)) / 2];
      }
    }
#pragma unroll
    for (int i = 0; i < 4; ++i)
#pragma unroll
      for (int jn = 0; jn < 4; ++jn) {
        acc[i][jn] = __builtin_amdgcn_mfma_f32_16x16x32_bf16(af[i][0], bfr[jn][0], acc[i][jn], 0, 0, 0);
        acc[i][jn] = __builtin_amdgcn_mfma_f32_16x16x32_bf16(af[i][1], bfr[jn][1], acc[i][jn], 0, 0, 0);
      }
    __syncthreads();
    cur ^= 1;
  }

  if (MODE == 0) {
#pragma unroll
    for (int i = 0; i < 4; ++i) {
      const int tok0 = m0 + wm * 64 + i * 16 + g * 4;  // +r
      const int bq = tok0 >> 11;
      const int nn0 = tok0 & 2047;
#pragma unroll
      for (int jn = 0; jn < 4; ++jn) {
        const int c = c0 + wn * 64 + jn * 16 + n16;
        if (c < 512) {
          const int h = c >> 6, dk = c & 63;
          unsigned short* qp = qb + (((size_t)bq * 8 + h) * 2048 + nn0) * 64 + dk;
#pragma unroll
          for (int r = 0; r < 4; ++r) qp[(size_t)r * 64] = f2bf(acc[i][jn][r]);
        } else if (c < 1024) {
          const int c2 = c - 512, h = c2 >> 6, dk = c2 & 63;
          unsigned short* kp = kb + (((size_t)bq * 8 + h) * 2048 + nn0) * 64 + dk;
#pragma unroll
          for (int r = 0; r < 4; ++r) kp[(size_t)r * 64] = f2bf(acc[i][jn][r]);
        } else {
          const int c2 = c - 1024, h = c2 >> 6, dk = c2 & 63;
          ushort4 pk;
          pk.x = f2bf(acc[i][jn][0]); pk.y = f2bf(acc[i][jn][1]);
          pk.z = f2bf(acc[i][jn][2]); pk.w = f2bf(acc[i][jn][3]);
          *(ushort4*)(vt + (((size_t)bq * 8 + h) * 64 + dk) * 2048 + nn0) = pk;  // V^T, n-contig
        }
      }
    }
  } else {
#pragma unroll
    for (int jn = 0; jn < 4; ++jn) {
      const int c = c0 + wn * 64 + jn * 16 + n16;
      const float bc = bias[c];
#pragma unroll
      for (int i = 0; i < 4; ++i) {
        const int tok0 = m0 + wm * 64 + i * 16 + g * 4;
#pragma unroll
        for (int r = 0; r < 4; ++r) {
          float v = acc[i][jn][r] + bc;
          v = v >= 0.f ? v : 0.1f * v;               // LeakyReLU
          outp[(size_t)(tok0 + r) * 512 + c] = v;
        }
      }
    }
  }
}

// ---- flash attention: block = 4 waves x 16 q-rows, KV tile 64, dbuf LDS ----
__global__ __launch_bounds__(256, 4) void attn_kernel(
    const unsigned short* __restrict__ qb, const unsigned short* __restrict__ kb,
    const unsigned short* __restrict__ vt, const unsigned long long* __restrict__ mp,
    unsigned short* __restrict__ ao) {
  __shared__ unsigned short Kl[2][4096];  // [m 64][k 64] (swizzled slots)
  __shared__ unsigned short Vl[2][4096];  // [dk 64][m 64]
  __shared__ unsigned short Pl[4][1024];  // per-wave [n 16][m 64]
  const int tid = threadIdx.x, lane = tid & 63, wv = tid >> 6;
  const int g = lane >> 4, n16 = lane & 15;
  const int qt = blockIdx.x & 31, bh = blockIdx.x >> 5;
  const int b = bh >> 3, h = bh & 7;
  const int n0 = qt * 64 + wv * 16;
  const unsigned short* Qh = qb + (size_t)bh * 2048 * 64;
  const unsigned short* Kh = kb + (size_t)bh * 2048 * 64;
  const unsigned short* Vh = vt + (size_t)bh * 64 * 2048;
  const unsigned long long* mrow = mp + ((size_t)b * 2048 + n0 + n16) * 32;

  // Q fragments (B-operand of swapped QK^T): row n=lane&15, k-contig
  const s16x8 qf0 = *(const s16x8*)&Qh[(size_t)(n0 + n16) * 64 + g * 8];
  const s16x8 qf1 = *(const s16x8*)&Qh[(size_t)(n0 + n16) * 64 + 32 + g * 8];

  float mrun = -1e30f, lrun = 0.f;
  f32x4 of[4] = {};

  auto stage = [&](int buf, int m0) {
#pragma unroll
    for (int j = 0; j < 2; ++j) {
      const int base = (wv * 2 + j) * 1024;
      const int o = base + lane * 16;
      const int r = o >> 7;
      const int sl = ((o >> 4) & 7) ^ (r & 7);
      const unsigned short* gk = Kh + (size_t)(m0 + r) * 64 + sl * 8;
      __builtin_amdgcn_global_load_lds(
          (const __attribute__((address_space(1))) uint32_t*)gk,
          (__attribute__((address_space(3))) uint32_t*)&Kl[buf][base / 2], 16, 0, 0);
      const unsigned short* gv = Vh + (size_t)r * 2048 + m0 + sl * 8;
      __builtin_amdgcn_global_load_lds(
          (const __attribute__((address_space(1))) uint32_t*)gv,
          (__attribute__((address_space(3))) uint32_t*)&Vl[buf][base / 2], 16, 0, 0);
    }
  };

  stage(0, 0);
  __syncthreads();
  int cur = 0;
  for (int it = 0; it < 32; ++it) {
    if (it < 31) stage(cur ^ 1, (it + 1) * 64);
    const unsigned long long wbits = mrow[it];

    // S^T = K · Q : lane holds S[m = 16mf+4g+r][n = n16]
    f32x4 sc[4] = {};
#pragma unroll
    for (int mf = 0; mf < 4; ++mf) {
      const int ml = mf * 16 + n16;
#pragma unroll
      for (int kc = 0; kc < 2; ++kc) {
        const int sl = kc * 4 + g;
        const s16x8 kf = *(const s16x8*)&Kl[cur][(ml * 128 + ((sl ^ (ml & 7)) * 16)) / 2];
        sc[mf] = __builtin_amdgcn_mfma_f32_16x16x32_bf16(kf, kc ? qf1 : qf0, sc[mf], 0, 0, 0);
      }
    }

    // masked online softmax (row n = n16, values spread over 4 lane-groups)
    float sv[16];
    float tmax = -1e30f;
#pragma unroll
    for (int mf = 0; mf < 4; ++mf)
#pragma unroll
      for (int r = 0; r < 4; ++r) {
        const int mloc = mf * 16 + g * 4 + r;
        float v = sc[mf][r] * 0.125f;                       // 1/sqrt(64)
        v = ((wbits >> mloc) & 1ull) ? v : -1e30f;
        sv[mf * 4 + r] = v;
        tmax = fmaxf(tmax, v);
      }
    tmax = fmaxf(tmax, __shfl_xor(tmax, 16));
    tmax = fmaxf(tmax, __shfl_xor(tmax, 32));
    const float mnew = fmaxf(mrun, tmax);
    const float alpha = exp2f((mrun - mnew) * 1.44269504f); // all-masked prefix self-corrects (alpha->0)
    float tsum = 0.f;
    unsigned short pb[16];
#pragma unroll
    for (int i2 = 0; i2 < 16; ++i2) {
      const float p = exp2f((sv[i2] - mnew) * 1.44269504f);
      tsum += p;
      pb[i2] = f2bf(p);
    }
    tsum += __shfl_xor(tsum, 16);
    tsum += __shfl_xor(tsum, 32);
    lrun = lrun * alpha + tsum;
    mrun = mnew;

    // rescale O (O rows live at n = 4g+r)
    float arow[4];
#pragma unroll
    for (int r = 0; r < 4; ++r) arow[r] = __shfl(alpha, 4 * g + r);
#pragma unroll
    for (int df = 0; df < 4; ++df) {
      of[df][0] *= arow[0]; of[df][1] *= arow[1];
      of[df][2] *= arow[2]; of[df][3] *= arow[3];
    }

    // P^T -> per-wave LDS (XOR-swizzled), re-fragment as PV A-operand
    unsigned short* Pw = Pl[wv];
#pragma unroll
    for (int mf = 0; mf < 4; ++mf) {
      int bo = n16 * 128 + mf * 32 + g * 8;
      bo ^= (n16 & 7) << 4;
      ushort4 pk;
      pk.x = pb[mf * 4]; pk.y = pb[mf * 4 + 1]; pk.z = pb[mf * 4 + 2]; pk.w = pb[mf * 4 + 3];
      *(ushort4*)((char*)Pw + bo) = pk;
    }
#pragma unroll
    for (int kc = 0; kc < 2; ++kc) {
      int bo = n16 * 128 + kc * 64 + g * 16;
      bo ^= (n16 & 7) << 4;
      const s16x8 pf = *(const s16x8*)((const char*)Pw + bo);
#pragma unroll
      for (int df = 0; df < 4; ++df) {
        const int dk = df * 16 + n16;
        const int sl = kc * 4 + g;
        const s16x8 vf = *(const s16x8*)&Vl[cur][(dk * 128 + ((sl ^ (dk & 7)) * 16)) / 2];
        of[df] = __builtin_amdgcn_mfma_f32_16x16x32_bf16(pf, vf, of[df], 0, 0, 0);
      }
    }
    __syncthreads();
    cur ^= 1;
  }

  float rinv[4];
#pragma unroll
  for (int r = 0; r < 4; ++r) rinv[r] = 1.f / __shfl(lrun, 4 * g + r);
#pragma unroll
  for (int df = 0; df < 4; ++df)
#pragma unroll
    for (int r = 0; r < 4; ++r) {
      const int token = b * 2048 + n0 + 4 * g + r;
      ao[(size_t)token * 512 + h * 64 + df * 16 + n16] = f2bf(of[df][r] * rinv[r]);
    }
}

extern "C" void kernel_launch(void* const* d_in, const int* in_sizes, int n_in,
                              void* d_out, int out_size, void* d_ws, size_t ws_size,
                              hipStream_t stream) {
  const float* x = (const float*)d_in[0];
  const void* mask = d_in[1];
  const float* Wqkv = (const float*)d_in[2];
  const float* Wout = (const float*)d_in[3];
  const float* bout = (const float*)d_in[4];
  float* out = (float*)d_out;
  char* ws = (char*)d_ws;

  int* flag = (int*)(ws + OFF_FLAG);
  unsigned short* xb = (unsigned short*)(ws + OFF_XB);
  unsigned short* wqkvT = (unsigned short*)(ws + OFF_WQKVT);
  unsigned short* woutT = (unsigned short*)(ws + OFF_WOUTT);
  unsigned long long* mp = (unsigned long long*)(ws + OFF_MASKP);
  unsigned short* qb = (unsigned short*)(ws + OFF_Q);
  unsigned short* kb = (unsigned short*)(ws + OFF_K);
  unsigned short* vt = (unsigned short*)(ws + OFF_VT);
  unsigned short* ao = (unsigned short*)(ws + OFF_AO);

  detect_mask_kernel<<<1, 64, 0, stream>>>((const unsigned char*)mask, flag);
  cvt_x_kernel<<<2048, 256, 0, stream>>>(x, xb, BN * Dd / 4);
  cvt_wT_kernel<<<1024, 256, 0, stream>>>(Wqkv, wqkvT, Dd, 3 * Dd);
  cvt_wT_kernel<<<512, 256, 0, stream>>>(Wout, woutT, Dd, Dd);
  pack_mask_kernel<<<1024, 256, 0, stream>>>((const unsigned char*)mask, (const int*)mask,
                                             flag, mp, Bb * Nn * (Nn / 64));
  gemm128<0><<<dim3(64, 12), 256, 0, stream>>>(xb, wqkvT, qb, kb, vt, nullptr, nullptr);
  attn_kernel<<<1024, 256, 0, stream>>>(qb, kb, vt, mp, ao);
  gemm128<1><<<dim3(64, 4), 256, 0, stream>>>(ao, woutT, nullptr, nullptr, nullptr, bout, out);
}